// Round 1
// baseline (1108.066 us; speedup 1.0000x reference)
//
#include <hip/hip_runtime.h>
#include <hip/hip_bf16.h>

#define N_NODES 50000
#define N_EDGES 800000
#define E_TOT   850000   // edges + self loops
#define N_GRAPHS 64
#define HID 512

// ---------------------------------------------------------------- CSR build
__global__ __launch_bounds__(256) void count_kernel(const int* __restrict__ dst_e,
                                                    int* __restrict__ cnt) {
    int e = blockIdx.x * 256 + threadIdx.x;
    if (e >= E_TOT) return;
    int d = (e < N_EDGES) ? dst_e[e] : (e - N_EDGES);
    atomicAdd(&cnt[d], 1);
}

// block-local exclusive scan of 256 counts; writes exclusive prefix into out, block total into blocksum
__global__ __launch_bounds__(256) void scan_local(const int* __restrict__ cnt,
                                                  int* __restrict__ out,
                                                  int* __restrict__ blocksum, int n) {
    __shared__ int buf[256];
    int tid = threadIdx.x;
    int i = blockIdx.x * 256 + tid;
    int v = (i < n) ? cnt[i] : 0;
    buf[tid] = v;
    __syncthreads();
    for (int off = 1; off < 256; off <<= 1) {
        int t = (tid >= off) ? buf[tid - off] : 0;
        __syncthreads();
        buf[tid] += t;
        __syncthreads();
    }
    if (i < n) out[i] = buf[tid] - v;            // exclusive
    if (tid == 255) blocksum[blockIdx.x] = buf[255];
}

// single-block scan of block sums (nb <= 256); also writes grand total to *total_ptr
__global__ __launch_bounds__(256) void scan_block(const int* __restrict__ blocksum,
                                                  int* __restrict__ blockoff, int nb,
                                                  int* __restrict__ total_ptr) {
    __shared__ int buf[256];
    int tid = threadIdx.x;
    int v = (tid < nb) ? blocksum[tid] : 0;
    buf[tid] = v;
    __syncthreads();
    for (int off = 1; off < 256; off <<= 1) {
        int t = (tid >= off) ? buf[tid - off] : 0;
        __syncthreads();
        buf[tid] += t;
        __syncthreads();
    }
    blockoff[tid] = buf[tid] - v;                // exclusive
    if (tid == 255) *total_ptr = buf[255];
}

__global__ __launch_bounds__(256) void scan_add(int* __restrict__ row_ptr,
                                                const int* __restrict__ blockoff, int n) {
    int i = blockIdx.x * 256 + threadIdx.x;
    if (i < n) row_ptr[i] += blockoff[blockIdx.x];
}

__global__ __launch_bounds__(256) void fill_kernel(const int* __restrict__ edge_index,
                                                   const int* __restrict__ row_ptr,
                                                   int* __restrict__ off,
                                                   int* __restrict__ col_idx) {
    int e = blockIdx.x * 256 + threadIdx.x;
    if (e >= E_TOT) return;
    int s, d;
    if (e < N_EDGES) { s = edge_index[e]; d = edge_index[N_EDGES + e]; }
    else             { s = e - N_EDGES;   d = s; }
    int pos = row_ptr[d] + atomicAdd(&off[d], 1);
    col_idx[pos] = s;
}

// ---------------------------------------------------------------- SGEMM (f32)
// C[M,N] = A[M,K] @ B[K,N].  BM=BN=64, BK=16, 256 threads, 4x4 per thread.
__global__ __launch_bounds__(256) void sgemm_kernel(const float* __restrict__ A,
                                                    const float* __restrict__ B,
                                                    float* __restrict__ C,
                                                    int M, int N, int K) {
    __shared__ float As[16][64];
    __shared__ float Bs[16][64];
    const int bm = blockIdx.x * 64;
    const int bn = blockIdx.y * 64;
    const int tid = threadIdx.x;
    const int tx = tid & 15;
    const int ty = tid >> 4;
    const int la_m = tid >> 2;           // 0..63
    const int la_k = (tid & 3) << 2;     // 0,4,8,12
    const int lb_k = tid >> 4;           // 0..15
    const int lb_n = (tid & 15) << 2;    // 0..60
    float acc[4][4] = {};
    for (int k0 = 0; k0 < K; k0 += 16) {
        float4 av = make_float4(0.f, 0.f, 0.f, 0.f);
        if (bm + la_m < M)
            av = *(const float4*)(A + (size_t)(bm + la_m) * K + k0 + la_k);
        As[la_k + 0][la_m] = av.x;
        As[la_k + 1][la_m] = av.y;
        As[la_k + 2][la_m] = av.z;
        As[la_k + 3][la_m] = av.w;
        float4 bv = *(const float4*)(B + (size_t)(k0 + lb_k) * N + bn + lb_n);
        *(float4*)&Bs[lb_k][lb_n] = bv;
        __syncthreads();
#pragma unroll
        for (int kk = 0; kk < 16; ++kk) {
            float a[4], b[4];
#pragma unroll
            for (int i = 0; i < 4; ++i) a[i] = As[kk][ty * 4 + i];
#pragma unroll
            for (int j = 0; j < 4; ++j) b[j] = Bs[kk][tx * 4 + j];
#pragma unroll
            for (int i = 0; i < 4; ++i)
#pragma unroll
                for (int j = 0; j < 4; ++j) acc[i][j] += a[i] * b[j];
        }
        __syncthreads();
    }
#pragma unroll
    for (int i = 0; i < 4; ++i) {
        int r = bm + ty * 4 + i;
        if (r < M) {
            float4 v = make_float4(acc[i][0], acc[i][1], acc[i][2], acc[i][3]);
            *(float4*)(C + (size_t)r * N + bn + tx * 4) = v;
        }
    }
}

// ---------------------------------------------------------------- attention projections
// ls[n] = h[n,:] . att[0,:],  ld[n] = h[n,:] . att[1,:]
__global__ __launch_bounds__(256) void att_kernel(const float* __restrict__ H,
                                                  const float* __restrict__ att,
                                                  float* __restrict__ ls,
                                                  float* __restrict__ ld, int D) {
    __shared__ float r0[256], r1[256];
    int n = blockIdx.x;
    int tid = threadIdx.x;
    float a0 = 0.f, a1 = 0.f;
    for (int f = tid; f < D; f += 256) {
        float h = H[(size_t)n * D + f];
        a0 += h * att[f];
        a1 += h * att[D + f];
    }
    r0[tid] = a0; r1[tid] = a1;
    __syncthreads();
    for (int off = 128; off > 0; off >>= 1) {
        if (tid < off) { r0[tid] += r0[tid + off]; r1[tid] += r1[tid + off]; }
        __syncthreads();
    }
    if (tid == 0) { ls[n] = r0[0]; ld[n] = r1[0]; }
}

// ---------------------------------------------------------------- GAT aggregation
// One block per dst node i: segment softmax over incoming edges + weighted sum of h[src].
template <int D>
__global__ __launch_bounds__(256) void aggregate_kernel(const float* __restrict__ H,
                                                        const float* __restrict__ ls,
                                                        const float* __restrict__ ld,
                                                        const int* __restrict__ row_ptr,
                                                        const int* __restrict__ col_idx,
                                                        const float* __restrict__ bias,
                                                        float* __restrict__ out) {
    constexpr int EG = 256 / D;   // edges processed in parallel in phase C
    __shared__ float red[256];
    const int i = blockIdx.x;
    const int tid = threadIdx.x;
    const int start = row_ptr[i];
    const int end = row_ptr[i + 1];
    const float ldi = ld[i];

    // phase A: max logit
    float lmax = -3.0e38f;
    for (int e = start + tid; e < end; e += 256) {
        float l = ls[col_idx[e]] + ldi;
        l = (l > 0.f) ? l : 0.2f * l;
        lmax = fmaxf(lmax, l);
    }
    red[tid] = lmax;
    __syncthreads();
    for (int off = 128; off > 0; off >>= 1) {
        if (tid < off) red[tid] = fmaxf(red[tid], red[tid + off]);
        __syncthreads();
    }
    const float m = red[0];
    __syncthreads();

    // phase B: sum of exp
    float lsum = 0.f;
    for (int e = start + tid; e < end; e += 256) {
        float l = ls[col_idx[e]] + ldi;
        l = (l > 0.f) ? l : 0.2f * l;
        lsum += __expf(l - m);
    }
    red[tid] = lsum;
    __syncthreads();
    for (int off = 128; off > 0; off >>= 1) {
        if (tid < off) red[tid] += red[tid + off];
        __syncthreads();
    }
    const float inv_s = 1.0f / red[0];
    __syncthreads();

    // phase C: weighted gather
    const int g = tid / D;
    const int f = tid % D;
    float acc = 0.f;
    for (int e0 = start; e0 < end; e0 += EG) {
        int e = e0 + g;
        if (e < end) {
            int src = col_idx[e];
            float l = ls[src] + ldi;
            l = (l > 0.f) ? l : 0.2f * l;
            float coef = __expf(l - m) * inv_s;
            acc += coef * H[(size_t)src * D + f];
        }
    }
    if (EG > 1) {
        red[tid] = acc;
        __syncthreads();
        if (g == 0) {
#pragma unroll
            for (int gg = 1; gg < EG; ++gg) acc += red[gg * D + f];
        }
    }
    if (g == 0) {
        float v = acc + bias[f];
        out[(size_t)i * D + f] = (v > 0.f) ? v : 0.f;
    }
}

// ---------------------------------------------------------------- mean pool (sorted batch)
__device__ inline int lower_bound_dev(const int* __restrict__ a, int n, int v) {
    int lo = 0, hi = n;
    while (lo < hi) { int mid = (lo + hi) >> 1; if (a[mid] < v) lo = mid + 1; else hi = mid; }
    return lo;
}

#define POOL_SPLITS 32
__global__ __launch_bounds__(256) void pool_kernel(const float* __restrict__ x3,
                                                   const int* __restrict__ batch,
                                                   float* __restrict__ gsum,
                                                   int* __restrict__ gcnt) {
    int g = blockIdx.x;
    int split = blockIdx.y;
    int tid = threadIdx.x;
    int start = lower_bound_dev(batch, N_NODES, g);
    int end = lower_bound_dev(batch, N_NODES, g + 1);
    int nodes = end - start;
    int n0 = start + (int)((long long)nodes * split / POOL_SPLITS);
    int n1 = start + (int)((long long)nodes * (split + 1) / POOL_SPLITS);
    float acc = 0.f;
    for (int n = n0; n < n1; ++n) acc += x3[(size_t)n * 256 + tid];
    if (acc != 0.f) atomicAdd(&gsum[g * 256 + tid], acc);
    else atomicAdd(&gsum[g * 256 + tid], 0.f);  // keep deterministic work pattern
    if (split == 0 && tid == 0) gcnt[g] = nodes;
}

// ---------------------------------------------------------------- head MLP
__global__ __launch_bounds__(256) void fc1_kernel(const float* __restrict__ gsum,
                                                  const int* __restrict__ gcnt,
                                                  const float* __restrict__ w,
                                                  const float* __restrict__ b,
                                                  float* __restrict__ h1) {
    __shared__ float gc[256];
    int g = blockIdx.x;
    int tid = threadIdx.x;
    float denom = fmaxf((float)gcnt[g], 1.0f);
    gc[tid] = gsum[g * 256 + tid] / denom;
    __syncthreads();
#pragma unroll
    for (int jj = 0; jj < 2; ++jj) {
        int j = tid + jj * 256;
        float sum = b[j];
        for (int k = 0; k < 256; ++k) sum += gc[k] * w[k * HID + j];
        h1[g * HID + j] = (sum > 0.f) ? sum : 0.f;
    }
}

__global__ __launch_bounds__(256) void fc2_kernel(const float* __restrict__ h1,
                                                  const float* __restrict__ w,
                                                  const float* __restrict__ b,
                                                  float* __restrict__ out) {
    __shared__ float red[256];
    int g = blockIdx.x;
    int tid = threadIdx.x;
    float acc = h1[g * HID + tid] * w[tid] + h1[g * HID + tid + 256] * w[tid + 256];
    red[tid] = acc;
    __syncthreads();
    for (int off = 128; off > 0; off >>= 1) {
        if (tid < off) red[tid] += red[tid + off];
        __syncthreads();
    }
    if (tid == 0) out[g] = red[0] + b[0];
}

// ---------------------------------------------------------------- launch
extern "C" void kernel_launch(void* const* d_in, const int* in_sizes, int n_in,
                              void* d_out, int out_size, void* d_ws, size_t ws_size,
                              hipStream_t stream) {
    const float* feature  = (const float*)d_in[0];
    const int*   edge_idx = (const int*)d_in[1];
    const int*   batch    = (const int*)d_in[2];
    const float* W1    = (const float*)d_in[3];
    const float* att1  = (const float*)d_in[4];
    const float* b1    = (const float*)d_in[5];
    const float* W2    = (const float*)d_in[6];
    const float* att2  = (const float*)d_in[7];
    const float* b2    = (const float*)d_in[8];
    const float* W3    = (const float*)d_in[9];
    const float* att3  = (const float*)d_in[10];
    const float* b3    = (const float*)d_in[11];
    const float* fc1_w = (const float*)d_in[12];
    const float* fc1_b = (const float*)d_in[13];
    const float* fc2_w = (const float*)d_in[14];
    const float* fc2_b = (const float*)d_in[15];
    float* out = (float*)d_out;

    char* w = (char*)d_ws;
    auto alloc = [&](size_t bytes) {
        char* p = w;
        w += (bytes + 255) & ~(size_t)255;
        return p;
    };
    float* X    = (float*)alloc((size_t)N_NODES * 256 * 4);
    float* H    = (float*)alloc((size_t)N_NODES * 256 * 4);
    float* ls   = (float*)alloc((size_t)N_NODES * 4);
    float* ld   = (float*)alloc((size_t)N_NODES * 4);
    float* gsum = (float*)alloc(64 * 256 * 4);
    float* h1   = (float*)alloc(64 * HID * 4);
    int* cnt      = (int*)alloc((size_t)N_NODES * 4);
    int* offbuf   = (int*)alloc((size_t)N_NODES * 4);
    int* row_ptr  = (int*)alloc((size_t)(N_NODES + 1) * 4);
    int* col_idx  = (int*)alloc((size_t)E_TOT * 4);
    int* blocksum = (int*)alloc(256 * 4);
    int* blockoff = (int*)alloc(256 * 4);
    int* gcnt     = (int*)alloc(64 * 4);

    hipMemsetAsync(cnt, 0, (size_t)N_NODES * 4, stream);
    hipMemsetAsync(offbuf, 0, (size_t)N_NODES * 4, stream);
    hipMemsetAsync(gsum, 0, 64 * 256 * 4, stream);

    const int EB = (E_TOT + 255) / 256;       // 3321
    const int NB = (N_NODES + 255) / 256;     // 196

    count_kernel<<<EB, 256, 0, stream>>>(edge_idx + N_EDGES, cnt);
    scan_local<<<NB, 256, 0, stream>>>(cnt, row_ptr, blocksum, N_NODES);
    scan_block<<<1, 256, 0, stream>>>(blocksum, blockoff, NB, row_ptr + N_NODES);
    scan_add<<<NB, 256, 0, stream>>>(row_ptr, blockoff, N_NODES);
    fill_kernel<<<EB, 256, 0, stream>>>(edge_idx, row_ptr, offbuf, col_idx);

    const int MB = (N_NODES + 63) / 64;       // 782

    // layer 1: D=64
    sgemm_kernel<<<dim3(MB, 1), 256, 0, stream>>>(feature, W1, H, N_NODES, 64, 64);
    att_kernel<<<N_NODES, 256, 0, stream>>>(H, att1, ls, ld, 64);
    aggregate_kernel<64><<<N_NODES, 256, 0, stream>>>(H, ls, ld, row_ptr, col_idx, b1, X);

    // layer 2: D=128
    sgemm_kernel<<<dim3(MB, 2), 256, 0, stream>>>(X, W2, H, N_NODES, 128, 64);
    att_kernel<<<N_NODES, 256, 0, stream>>>(H, att2, ls, ld, 128);
    aggregate_kernel<128><<<N_NODES, 256, 0, stream>>>(H, ls, ld, row_ptr, col_idx, b2, X);

    // layer 3: D=256
    sgemm_kernel<<<dim3(MB, 4), 256, 0, stream>>>(X, W3, H, N_NODES, 256, 128);
    att_kernel<<<N_NODES, 256, 0, stream>>>(H, att3, ls, ld, 256);
    aggregate_kernel<256><<<N_NODES, 256, 0, stream>>>(H, ls, ld, row_ptr, col_idx, b3, X);

    // pool + head
    pool_kernel<<<dim3(N_GRAPHS, POOL_SPLITS), 256, 0, stream>>>(X, batch, gsum, gcnt);
    fc1_kernel<<<N_GRAPHS, 256, 0, stream>>>(gsum, gcnt, fc1_w, fc1_b, h1);
    fc2_kernel<<<N_GRAPHS, 256, 0, stream>>>(h1, fc2_w, fc2_b, out);
}

// Round 2
// 559.583 us; speedup vs baseline: 1.9802x; 1.9802x over previous
//
#include <hip/hip_runtime.h>
#include <hip/hip_bf16.h>

#define N_NODES 50000
#define N_EDGES 800000
#define E_TOT   850000   // edges + self loops
#define N_GRAPHS 64
#define HID 512

// ---------------------------------------------------------------- CSR build
__global__ __launch_bounds__(256) void count_kernel(const int* __restrict__ dst_e,
                                                    int* __restrict__ cnt) {
    int e = blockIdx.x * 256 + threadIdx.x;
    if (e >= E_TOT) return;
    int d = (e < N_EDGES) ? dst_e[e] : (e - N_EDGES);
    atomicAdd(&cnt[d], 1);
}

__global__ __launch_bounds__(256) void scan_local(const int* __restrict__ cnt,
                                                  int* __restrict__ out,
                                                  int* __restrict__ blocksum, int n) {
    __shared__ int buf[256];
    int tid = threadIdx.x;
    int i = blockIdx.x * 256 + tid;
    int v = (i < n) ? cnt[i] : 0;
    buf[tid] = v;
    __syncthreads();
    for (int off = 1; off < 256; off <<= 1) {
        int t = (tid >= off) ? buf[tid - off] : 0;
        __syncthreads();
        buf[tid] += t;
        __syncthreads();
    }
    if (i < n) out[i] = buf[tid] - v;            // exclusive
    if (tid == 255) blocksum[blockIdx.x] = buf[255];
}

__global__ __launch_bounds__(256) void scan_block(const int* __restrict__ blocksum,
                                                  int* __restrict__ blockoff, int nb,
                                                  int* __restrict__ total_ptr) {
    __shared__ int buf[256];
    int tid = threadIdx.x;
    int v = (tid < nb) ? blocksum[tid] : 0;
    buf[tid] = v;
    __syncthreads();
    for (int off = 1; off < 256; off <<= 1) {
        int t = (tid >= off) ? buf[tid - off] : 0;
        __syncthreads();
        buf[tid] += t;
        __syncthreads();
    }
    blockoff[tid] = buf[tid] - v;                // exclusive
    if (tid == 255) *total_ptr = buf[255];
}

__global__ __launch_bounds__(256) void scan_add(int* __restrict__ row_ptr,
                                                const int* __restrict__ blockoff, int n) {
    int i = blockIdx.x * 256 + threadIdx.x;
    if (i < n) row_ptr[i] += blockoff[blockIdx.x];
}

__global__ __launch_bounds__(256) void fill_kernel(const int* __restrict__ edge_index,
                                                   const int* __restrict__ row_ptr,
                                                   int* __restrict__ off,
                                                   int* __restrict__ col_idx) {
    int e = blockIdx.x * 256 + threadIdx.x;
    if (e >= E_TOT) return;
    int s, d;
    if (e < N_EDGES) { s = edge_index[e]; d = edge_index[N_EDGES + e]; }
    else             { s = e - N_EDGES;   d = s; }
    int pos = row_ptr[d] + atomicAdd(&off[d], 1);
    col_idx[pos] = s;
}

// ---------------------------------------------------------------- SGEMM (f32)
__global__ __launch_bounds__(256) void sgemm_kernel(const float* __restrict__ A,
                                                    const float* __restrict__ B,
                                                    float* __restrict__ C,
                                                    int M, int N, int K) {
    __shared__ float As[16][64];
    __shared__ float Bs[16][64];
    const int bm = blockIdx.x * 64;
    const int bn = blockIdx.y * 64;
    const int tid = threadIdx.x;
    const int tx = tid & 15;
    const int ty = tid >> 4;
    const int la_m = tid >> 2;
    const int la_k = (tid & 3) << 2;
    const int lb_k = tid >> 4;
    const int lb_n = (tid & 15) << 2;
    float acc[4][4] = {};
    for (int k0 = 0; k0 < K; k0 += 16) {
        float4 av = make_float4(0.f, 0.f, 0.f, 0.f);
        if (bm + la_m < M)
            av = *(const float4*)(A + (size_t)(bm + la_m) * K + k0 + la_k);
        As[la_k + 0][la_m] = av.x;
        As[la_k + 1][la_m] = av.y;
        As[la_k + 2][la_m] = av.z;
        As[la_k + 3][la_m] = av.w;
        float4 bv = *(const float4*)(B + (size_t)(k0 + lb_k) * N + bn + lb_n);
        *(float4*)&Bs[lb_k][lb_n] = bv;
        __syncthreads();
#pragma unroll
        for (int kk = 0; kk < 16; ++kk) {
            float a[4], b[4];
#pragma unroll
            for (int i = 0; i < 4; ++i) a[i] = As[kk][ty * 4 + i];
#pragma unroll
            for (int j = 0; j < 4; ++j) b[j] = Bs[kk][tx * 4 + j];
#pragma unroll
            for (int i = 0; i < 4; ++i)
#pragma unroll
                for (int j = 0; j < 4; ++j) acc[i][j] += a[i] * b[j];
        }
        __syncthreads();
    }
#pragma unroll
    for (int i = 0; i < 4; ++i) {
        int r = bm + ty * 4 + i;
        if (r < M) {
            float4 v = make_float4(acc[i][0], acc[i][1], acc[i][2], acc[i][3]);
            *(float4*)(C + (size_t)r * N + bn + tx * 4) = v;
        }
    }
}

// ---------------------------------------------------------------- ls/ld projections (wave per node)
template <int D>
__global__ __launch_bounds__(256) void lsld_kernel(const float* __restrict__ H,
                                                   const float* __restrict__ att,
                                                   float* __restrict__ ls,
                                                   float* __restrict__ ld) {
    int wid = (blockIdx.x * 256 + threadIdx.x) >> 6;
    int lane = threadIdx.x & 63;
    if (wid >= N_NODES) return;
    float a0 = 0.f, a1 = 0.f;
#pragma unroll
    for (int f = lane; f < D; f += 64) {
        float h = H[(size_t)wid * D + f];
        a0 += h * att[f];
        a1 += h * att[D + f];
    }
#pragma unroll
    for (int off = 32; off > 0; off >>= 1) {
        a0 += __shfl_xor(a0, off);
        a1 += __shfl_xor(a1, off);
    }
    if (lane == 0) { ls[wid] = a0; ld[wid] = a1; }
}

// ---------------------------------------------------------------- per-edge softmax coefficients (wave per node)
__global__ __launch_bounds__(256) void coef_kernel(const float* __restrict__ ls,
                                                   const float* __restrict__ ld,
                                                   const int* __restrict__ row_ptr,
                                                   const int* __restrict__ col_idx,
                                                   float* __restrict__ coef) {
    int wid = (blockIdx.x * 256 + threadIdx.x) >> 6;
    int lane = threadIdx.x & 63;
    if (wid >= N_NODES) return;
    int start = row_ptr[wid];
    int end = row_ptr[wid + 1];
    int deg = end - start;
    float ldi = ld[wid];
    if (deg <= 64) {
        float l = -3.0e38f;
        if (lane < deg) {
            int s = col_idx[start + lane];
            l = ls[s] + ldi;
            l = (l > 0.f) ? l : 0.2f * l;
        }
        float m = l;
#pragma unroll
        for (int off = 32; off > 0; off >>= 1) m = fmaxf(m, __shfl_xor(m, off));
        float e = (lane < deg) ? __expf(l - m) : 0.f;
        float s = e;
#pragma unroll
        for (int off = 32; off > 0; off >>= 1) s += __shfl_xor(s, off);
        if (lane < deg) coef[start + lane] = e / s;
    } else {
        float m = -3.0e38f;
        for (int e = start + lane; e < end; e += 64) {
            int s = col_idx[e];
            float l = ls[s] + ldi;
            l = (l > 0.f) ? l : 0.2f * l;
            m = fmaxf(m, l);
        }
#pragma unroll
        for (int off = 32; off > 0; off >>= 1) m = fmaxf(m, __shfl_xor(m, off));
        float ssum = 0.f;
        for (int e = start + lane; e < end; e += 64) {
            int s = col_idx[e];
            float l = ls[s] + ldi;
            l = (l > 0.f) ? l : 0.2f * l;
            ssum += __expf(l - m);
        }
#pragma unroll
        for (int off = 32; off > 0; off >>= 1) ssum += __shfl_xor(ssum, off);
        float inv = 1.0f / ssum;
        for (int e = start + lane; e < end; e += 64) {
            int s = col_idx[e];
            float l = ls[s] + ldi;
            l = (l > 0.f) ? l : 0.2f * l;
            coef[e] = __expf(l - m) * inv;
        }
    }
}

// ---------------------------------------------------------------- weighted gather (wave per node, float4, 4-deep ILP)
template <int D>
__global__ __launch_bounds__(256) void gather_kernel(const float* __restrict__ H,
                                                     const float* __restrict__ coef,
                                                     const int* __restrict__ row_ptr,
                                                     const int* __restrict__ col_idx,
                                                     const float* __restrict__ bias,
                                                     float* __restrict__ out) {
    constexpr int L = D / 4;     // lanes per edge (row = L float4s)
    constexpr int P = 64 / L;    // edges handled concurrently by one wave
    int wid = (blockIdx.x * 256 + threadIdx.x) >> 6;
    int lane = threadIdx.x & 63;
    if (wid >= N_NODES) return;
    const int start = row_ptr[wid];
    const int end = row_ptr[wid + 1];
    const int eslot = lane / L;
    const int fidx = lane % L;
    const float4* __restrict__ H4 = (const float4*)H;
    float4 acc = make_float4(0.f, 0.f, 0.f, 0.f);

    int e0 = start;
    for (; e0 + 4 * P <= end; e0 += 4 * P) {
        int src[4]; float c[4]; float4 v[4];
#pragma unroll
        for (int j = 0; j < 4; ++j) {
            int e = e0 + j * P + eslot;
            src[j] = col_idx[e];
            c[j] = coef[e];
        }
#pragma unroll
        for (int j = 0; j < 4; ++j) v[j] = H4[(size_t)src[j] * L + fidx];
#pragma unroll
        for (int j = 0; j < 4; ++j) {
            acc.x += c[j] * v[j].x;
            acc.y += c[j] * v[j].y;
            acc.z += c[j] * v[j].z;
            acc.w += c[j] * v[j].w;
        }
    }
    for (; e0 < end; e0 += P) {
        int e = e0 + eslot;
        if (e < end) {
            int src = col_idx[e];
            float c = coef[e];
            float4 v = H4[(size_t)src * L + fidx];
            acc.x += c * v.x;
            acc.y += c * v.y;
            acc.z += c * v.z;
            acc.w += c * v.w;
        }
    }
#pragma unroll
    for (int m = L; m < 64; m <<= 1) {
        acc.x += __shfl_xor(acc.x, m);
        acc.y += __shfl_xor(acc.y, m);
        acc.z += __shfl_xor(acc.z, m);
        acc.w += __shfl_xor(acc.w, m);
    }
    if (eslot == 0) {
        float4 b = ((const float4*)bias)[fidx];
        float4 o;
        o.x = fmaxf(acc.x + b.x, 0.f);
        o.y = fmaxf(acc.y + b.y, 0.f);
        o.z = fmaxf(acc.z + b.z, 0.f);
        o.w = fmaxf(acc.w + b.w, 0.f);
        ((float4*)out)[(size_t)wid * L + fidx] = o;
    }
}

// ---------------------------------------------------------------- mean pool (sorted batch)
__device__ inline int lower_bound_dev(const int* __restrict__ a, int n, int v) {
    int lo = 0, hi = n;
    while (lo < hi) { int mid = (lo + hi) >> 1; if (a[mid] < v) lo = mid + 1; else hi = mid; }
    return lo;
}

#define POOL_SPLITS 32
__global__ __launch_bounds__(256) void pool_kernel(const float* __restrict__ x3,
                                                   const int* __restrict__ batch,
                                                   float* __restrict__ gsum,
                                                   int* __restrict__ gcnt) {
    int g = blockIdx.x;
    int split = blockIdx.y;
    int tid = threadIdx.x;
    int start = lower_bound_dev(batch, N_NODES, g);
    int end = lower_bound_dev(batch, N_NODES, g + 1);
    int nodes = end - start;
    int n0 = start + (int)((long long)nodes * split / POOL_SPLITS);
    int n1 = start + (int)((long long)nodes * (split + 1) / POOL_SPLITS);
    float acc = 0.f;
    for (int n = n0; n < n1; ++n) acc += x3[(size_t)n * 256 + tid];
    atomicAdd(&gsum[g * 256 + tid], acc);
    if (split == 0 && tid == 0) gcnt[g] = nodes;
}

// ---------------------------------------------------------------- head MLP
__global__ __launch_bounds__(256) void fc1_kernel(const float* __restrict__ gsum,
                                                  const int* __restrict__ gcnt,
                                                  const float* __restrict__ w,
                                                  const float* __restrict__ b,
                                                  float* __restrict__ h1) {
    __shared__ float gc[256];
    int g = blockIdx.x;
    int tid = threadIdx.x;
    float denom = fmaxf((float)gcnt[g], 1.0f);
    gc[tid] = gsum[g * 256 + tid] / denom;
    __syncthreads();
#pragma unroll
    for (int jj = 0; jj < 2; ++jj) {
        int j = tid + jj * 256;
        float sum = b[j];
        for (int k = 0; k < 256; ++k) sum += gc[k] * w[k * HID + j];
        h1[g * HID + j] = (sum > 0.f) ? sum : 0.f;
    }
}

__global__ __launch_bounds__(256) void fc2_kernel(const float* __restrict__ h1,
                                                  const float* __restrict__ w,
                                                  const float* __restrict__ b,
                                                  float* __restrict__ out) {
    __shared__ float red[256];
    int g = blockIdx.x;
    int tid = threadIdx.x;
    float acc = h1[g * HID + tid] * w[tid] + h1[g * HID + tid + 256] * w[tid + 256];
    red[tid] = acc;
    __syncthreads();
    for (int off = 128; off > 0; off >>= 1) {
        if (tid < off) red[tid] += red[tid + off];
        __syncthreads();
    }
    if (tid == 0) out[g] = red[0] + b[0];
}

// ---------------------------------------------------------------- launch
extern "C" void kernel_launch(void* const* d_in, const int* in_sizes, int n_in,
                              void* d_out, int out_size, void* d_ws, size_t ws_size,
                              hipStream_t stream) {
    const float* feature  = (const float*)d_in[0];
    const int*   edge_idx = (const int*)d_in[1];
    const int*   batch    = (const int*)d_in[2];
    const float* W1    = (const float*)d_in[3];
    const float* att1  = (const float*)d_in[4];
    const float* b1    = (const float*)d_in[5];
    const float* W2    = (const float*)d_in[6];
    const float* att2  = (const float*)d_in[7];
    const float* b2    = (const float*)d_in[8];
    const float* W3    = (const float*)d_in[9];
    const float* att3  = (const float*)d_in[10];
    const float* b3    = (const float*)d_in[11];
    const float* fc1_w = (const float*)d_in[12];
    const float* fc1_b = (const float*)d_in[13];
    const float* fc2_w = (const float*)d_in[14];
    const float* fc2_b = (const float*)d_in[15];
    float* out = (float*)d_out;

    char* w = (char*)d_ws;
    auto alloc = [&](size_t bytes) {
        char* p = w;
        w += (bytes + 255) & ~(size_t)255;
        return p;
    };
    float* X    = (float*)alloc((size_t)N_NODES * 256 * 4);
    float* H    = (float*)alloc((size_t)N_NODES * 256 * 4);
    float* ls   = (float*)alloc((size_t)N_NODES * 4);
    float* ld   = (float*)alloc((size_t)N_NODES * 4);
    float* coef = (float*)alloc((size_t)E_TOT * 4);
    float* gsum = (float*)alloc(64 * 256 * 4);
    float* h1   = (float*)alloc(64 * HID * 4);
    int* cnt      = (int*)alloc((size_t)N_NODES * 4);
    int* offbuf   = (int*)alloc((size_t)N_NODES * 4);
    int* row_ptr  = (int*)alloc((size_t)(N_NODES + 1) * 4);
    int* col_idx  = (int*)alloc((size_t)E_TOT * 4);
    int* blocksum = (int*)alloc(256 * 4);
    int* blockoff = (int*)alloc(256 * 4);
    int* gcnt     = (int*)alloc(64 * 4);

    hipMemsetAsync(cnt, 0, (size_t)N_NODES * 4, stream);
    hipMemsetAsync(offbuf, 0, (size_t)N_NODES * 4, stream);
    hipMemsetAsync(gsum, 0, 64 * 256 * 4, stream);

    const int EB = (E_TOT + 255) / 256;
    const int NB = (N_NODES + 255) / 256;
    const int WB = (N_NODES * 64 + 255) / 256;   // wave-per-node grids (12500)

    count_kernel<<<EB, 256, 0, stream>>>(edge_idx + N_EDGES, cnt);
    scan_local<<<NB, 256, 0, stream>>>(cnt, row_ptr, blocksum, N_NODES);
    scan_block<<<1, 256, 0, stream>>>(blocksum, blockoff, NB, row_ptr + N_NODES);
    scan_add<<<NB, 256, 0, stream>>>(row_ptr, blockoff, N_NODES);
    fill_kernel<<<EB, 256, 0, stream>>>(edge_idx, row_ptr, offbuf, col_idx);

    const int MB = (N_NODES + 63) / 64;

    // layer 1: D=64
    sgemm_kernel<<<dim3(MB, 1), 256, 0, stream>>>(feature, W1, H, N_NODES, 64, 64);
    lsld_kernel<64><<<WB, 256, 0, stream>>>(H, att1, ls, ld);
    coef_kernel<<<WB, 256, 0, stream>>>(ls, ld, row_ptr, col_idx, coef);
    gather_kernel<64><<<WB, 256, 0, stream>>>(H, coef, row_ptr, col_idx, b1, X);

    // layer 2: D=128
    sgemm_kernel<<<dim3(MB, 2), 256, 0, stream>>>(X, W2, H, N_NODES, 128, 64);
    lsld_kernel<128><<<WB, 256, 0, stream>>>(H, att2, ls, ld);
    coef_kernel<<<WB, 256, 0, stream>>>(ls, ld, row_ptr, col_idx, coef);
    gather_kernel<128><<<WB, 256, 0, stream>>>(H, coef, row_ptr, col_idx, b2, X);

    // layer 3: D=256
    sgemm_kernel<<<dim3(MB, 4), 256, 0, stream>>>(X, W3, H, N_NODES, 256, 128);
    lsld_kernel<256><<<WB, 256, 0, stream>>>(H, att3, ls, ld);
    coef_kernel<<<WB, 256, 0, stream>>>(ls, ld, row_ptr, col_idx, coef);
    gather_kernel<256><<<WB, 256, 0, stream>>>(H, coef, row_ptr, col_idx, b3, X);

    // pool + head
    pool_kernel<<<dim3(N_GRAPHS, POOL_SPLITS), 256, 0, stream>>>(X, batch, gsum, gcnt);
    fc1_kernel<<<N_GRAPHS, 256, 0, stream>>>(gsum, gcnt, fc1_w, fc1_b, h1);
    fc2_kernel<<<N_GRAPHS, 256, 0, stream>>>(h1, fc2_w, fc2_b, out);
}

// Round 3
// 522.700 us; speedup vs baseline: 2.1199x; 1.0706x over previous
//
#include <hip/hip_runtime.h>
#include <hip/hip_bf16.h>

#define N_NODES 50000
#define N_EDGES 800000
#define E_TOT   850000   // edges + self loops
#define N_GRAPHS 64
#define HID 512

// ---------------------------------------------------------------- CSR build
__global__ __launch_bounds__(256) void count_kernel(const int* __restrict__ dst_e,
                                                    int* __restrict__ cnt) {
    int e = blockIdx.x * 256 + threadIdx.x;
    if (e >= E_TOT) return;
    int d = (e < N_EDGES) ? dst_e[e] : (e - N_EDGES);
    atomicAdd(&cnt[d], 1);
}

__global__ __launch_bounds__(256) void scan_local(const int* __restrict__ cnt,
                                                  int* __restrict__ out,
                                                  int* __restrict__ blocksum, int n) {
    __shared__ int buf[256];
    int tid = threadIdx.x;
    int i = blockIdx.x * 256 + tid;
    int v = (i < n) ? cnt[i] : 0;
    buf[tid] = v;
    __syncthreads();
    for (int off = 1; off < 256; off <<= 1) {
        int t = (tid >= off) ? buf[tid - off] : 0;
        __syncthreads();
        buf[tid] += t;
        __syncthreads();
    }
    if (i < n) out[i] = buf[tid] - v;            // exclusive
    if (tid == 255) blocksum[blockIdx.x] = buf[255];
}

__global__ __launch_bounds__(256) void scan_block(const int* __restrict__ blocksum,
                                                  int* __restrict__ blockoff, int nb,
                                                  int* __restrict__ total_ptr) {
    __shared__ int buf[256];
    int tid = threadIdx.x;
    int v = (tid < nb) ? blocksum[tid] : 0;
    buf[tid] = v;
    __syncthreads();
    for (int off = 1; off < 256; off <<= 1) {
        int t = (tid >= off) ? buf[tid - off] : 0;
        __syncthreads();
        buf[tid] += t;
        __syncthreads();
    }
    blockoff[tid] = buf[tid] - v;                // exclusive
    if (tid == 255) *total_ptr = buf[255];
}

__global__ __launch_bounds__(256) void scan_add(int* __restrict__ row_ptr,
                                                const int* __restrict__ blockoff, int n) {
    int i = blockIdx.x * 256 + threadIdx.x;
    if (i < n) row_ptr[i] += blockoff[blockIdx.x];
}

__global__ __launch_bounds__(256) void fill_kernel(const int* __restrict__ edge_index,
                                                   const int* __restrict__ row_ptr,
                                                   int* __restrict__ off,
                                                   int* __restrict__ col_idx) {
    int e = blockIdx.x * 256 + threadIdx.x;
    if (e >= E_TOT) return;
    int s, d;
    if (e < N_EDGES) { s = edge_index[e]; d = edge_index[N_EDGES + e]; }
    else             { s = e - N_EDGES;   d = s; }
    int pos = row_ptr[d] + atomicAdd(&off[d], 1);
    col_idx[pos] = s;
}

// ---------------------------------------------------------------- fold attention into input space
// wsd[0:Din] = W @ att[0,:],  wsd[Din:2Din] = W @ att[1,:]
__global__ __launch_bounds__(256) void fold_att_kernel(const float* __restrict__ W,
                                                       const float* __restrict__ att,
                                                       float* __restrict__ wsd,
                                                       int Din, int Dout) {
    int tid = threadIdx.x;
    for (int k = tid; k < 2 * Din; k += 256) {
        int half = (k >= Din) ? 1 : 0;
        int row = (k >= Din) ? (k - Din) : k;
        float s = 0.f;
        for (int j = 0; j < Dout; ++j) s += W[(size_t)row * Dout + j] * att[half * Dout + j];
        wsd[k] = s;
    }
}

// ---------------------------------------------------------------- SGEMM (f32) with optional bias+relu epilogue
__global__ __launch_bounds__(256) void sgemm_kernel(const float* __restrict__ A,
                                                    const float* __restrict__ B,
                                                    float* __restrict__ C,
                                                    const float* __restrict__ bias,
                                                    int M, int N, int K) {
    __shared__ float As[16][64];
    __shared__ float Bs[16][64];
    const int bm = blockIdx.x * 64;
    const int bn = blockIdx.y * 64;
    const int tid = threadIdx.x;
    const int tx = tid & 15;
    const int ty = tid >> 4;
    const int la_m = tid >> 2;
    const int la_k = (tid & 3) << 2;
    const int lb_k = tid >> 4;
    const int lb_n = (tid & 15) << 2;
    float acc[4][4] = {};
    for (int k0 = 0; k0 < K; k0 += 16) {
        float4 av = make_float4(0.f, 0.f, 0.f, 0.f);
        if (bm + la_m < M)
            av = *(const float4*)(A + (size_t)(bm + la_m) * K + k0 + la_k);
        As[la_k + 0][la_m] = av.x;
        As[la_k + 1][la_m] = av.y;
        As[la_k + 2][la_m] = av.z;
        As[la_k + 3][la_m] = av.w;
        float4 bv = *(const float4*)(B + (size_t)(k0 + lb_k) * N + bn + lb_n);
        *(float4*)&Bs[lb_k][lb_n] = bv;
        __syncthreads();
#pragma unroll
        for (int kk = 0; kk < 16; ++kk) {
            float a[4], b[4];
#pragma unroll
            for (int i = 0; i < 4; ++i) a[i] = As[kk][ty * 4 + i];
#pragma unroll
            for (int j = 0; j < 4; ++j) b[j] = Bs[kk][tx * 4 + j];
#pragma unroll
            for (int i = 0; i < 4; ++i)
#pragma unroll
                for (int j = 0; j < 4; ++j) acc[i][j] += a[i] * b[j];
        }
        __syncthreads();
    }
    float4 bv = ((const float4*)bias)[(bn >> 2) + tx];
#pragma unroll
    for (int i = 0; i < 4; ++i) {
        int r = bm + ty * 4 + i;
        if (r < M) {
            float4 v;
            v.x = fmaxf(acc[i][0] + bv.x, 0.f);
            v.y = fmaxf(acc[i][1] + bv.y, 0.f);
            v.z = fmaxf(acc[i][2] + bv.z, 0.f);
            v.w = fmaxf(acc[i][3] + bv.w, 0.f);
            *(float4*)(C + (size_t)r * N + bn + tx * 4) = v;
        }
    }
}

// ---------------------------------------------------------------- ls/ld projections from input x (wave per node)
template <int D>
__global__ __launch_bounds__(256) void lsld_kernel(const float* __restrict__ X,
                                                   const float* __restrict__ wsd,
                                                   float* __restrict__ ls,
                                                   float* __restrict__ ld) {
    int wid = (blockIdx.x * 256 + threadIdx.x) >> 6;
    int lane = threadIdx.x & 63;
    if (wid >= N_NODES) return;
    float a0 = 0.f, a1 = 0.f;
#pragma unroll
    for (int f = lane; f < D; f += 64) {
        float h = X[(size_t)wid * D + f];
        a0 += h * wsd[f];
        a1 += h * wsd[D + f];
    }
#pragma unroll
    for (int off = 32; off > 0; off >>= 1) {
        a0 += __shfl_xor(a0, off);
        a1 += __shfl_xor(a1, off);
    }
    if (lane == 0) { ls[wid] = a0; ld[wid] = a1; }
}

// ---------------------------------------------------------------- per-edge softmax coefficients (wave per node)
__global__ __launch_bounds__(256) void coef_kernel(const float* __restrict__ ls,
                                                   const float* __restrict__ ld,
                                                   const int* __restrict__ row_ptr,
                                                   const int* __restrict__ col_idx,
                                                   float* __restrict__ coef) {
    int wid = (blockIdx.x * 256 + threadIdx.x) >> 6;
    int lane = threadIdx.x & 63;
    if (wid >= N_NODES) return;
    int start = row_ptr[wid];
    int end = row_ptr[wid + 1];
    int deg = end - start;
    float ldi = ld[wid];
    if (deg <= 64) {
        float l = -3.0e38f;
        if (lane < deg) {
            int s = col_idx[start + lane];
            l = ls[s] + ldi;
            l = (l > 0.f) ? l : 0.2f * l;
        }
        float m = l;
#pragma unroll
        for (int off = 32; off > 0; off >>= 1) m = fmaxf(m, __shfl_xor(m, off));
        float e = (lane < deg) ? __expf(l - m) : 0.f;
        float s = e;
#pragma unroll
        for (int off = 32; off > 0; off >>= 1) s += __shfl_xor(s, off);
        if (lane < deg) coef[start + lane] = e / s;
    } else {
        float m = -3.0e38f;
        for (int e = start + lane; e < end; e += 64) {
            int s = col_idx[e];
            float l = ls[s] + ldi;
            l = (l > 0.f) ? l : 0.2f * l;
            m = fmaxf(m, l);
        }
#pragma unroll
        for (int off = 32; off > 0; off >>= 1) m = fmaxf(m, __shfl_xor(m, off));
        float ssum = 0.f;
        for (int e = start + lane; e < end; e += 64) {
            int s = col_idx[e];
            float l = ls[s] + ldi;
            l = (l > 0.f) ? l : 0.2f * l;
            ssum += __expf(l - m);
        }
#pragma unroll
        for (int off = 32; off > 0; off >>= 1) ssum += __shfl_xor(ssum, off);
        float inv = 1.0f / ssum;
        for (int e = start + lane; e < end; e += 64) {
            int s = col_idx[e];
            float l = ls[s] + ldi;
            l = (l > 0.f) ? l : 0.2f * l;
            coef[e] = __expf(l - m) * inv;
        }
    }
}

// ---------------------------------------------------------------- weighted gather on INPUT x (wave per node, float4, 4-deep ILP)
template <int D>
__global__ __launch_bounds__(256) void gather_kernel(const float* __restrict__ X,
                                                     const float* __restrict__ coef,
                                                     const int* __restrict__ row_ptr,
                                                     const int* __restrict__ col_idx,
                                                     float* __restrict__ out) {
    constexpr int L = D / 4;     // lanes per edge
    constexpr int P = 64 / L;    // edges handled concurrently by one wave
    int wid = (blockIdx.x * 256 + threadIdx.x) >> 6;
    int lane = threadIdx.x & 63;
    if (wid >= N_NODES) return;
    const int start = row_ptr[wid];
    const int end = row_ptr[wid + 1];
    const int eslot = lane / L;
    const int fidx = lane % L;
    const float4* __restrict__ X4 = (const float4*)X;
    float4 acc = make_float4(0.f, 0.f, 0.f, 0.f);

    int e0 = start;
    for (; e0 + 4 * P <= end; e0 += 4 * P) {
        int src[4]; float c[4]; float4 v[4];
#pragma unroll
        for (int j = 0; j < 4; ++j) {
            int e = e0 + j * P + eslot;
            src[j] = col_idx[e];
            c[j] = coef[e];
        }
#pragma unroll
        for (int j = 0; j < 4; ++j) v[j] = X4[(size_t)src[j] * L + fidx];
#pragma unroll
        for (int j = 0; j < 4; ++j) {
            acc.x += c[j] * v[j].x;
            acc.y += c[j] * v[j].y;
            acc.z += c[j] * v[j].z;
            acc.w += c[j] * v[j].w;
        }
    }
    for (; e0 < end; e0 += P) {
        int e = e0 + eslot;
        if (e < end) {
            int src = col_idx[e];
            float c = coef[e];
            float4 v = X4[(size_t)src * L + fidx];
            acc.x += c * v.x;
            acc.y += c * v.y;
            acc.z += c * v.z;
            acc.w += c * v.w;
        }
    }
#pragma unroll
    for (int m = L; m < 64; m <<= 1) {
        acc.x += __shfl_xor(acc.x, m);
        acc.y += __shfl_xor(acc.y, m);
        acc.z += __shfl_xor(acc.z, m);
        acc.w += __shfl_xor(acc.w, m);
    }
    if (eslot == 0)
        ((float4*)out)[(size_t)wid * L + fidx] = acc;
}

// ---------------------------------------------------------------- mean pool (sorted batch)
__device__ inline int lower_bound_dev(const int* __restrict__ a, int n, int v) {
    int lo = 0, hi = n;
    while (lo < hi) { int mid = (lo + hi) >> 1; if (a[mid] < v) lo = mid + 1; else hi = mid; }
    return lo;
}

#define POOL_SPLITS 32
__global__ __launch_bounds__(256) void pool_kernel(const float* __restrict__ x3,
                                                   const int* __restrict__ batch,
                                                   float* __restrict__ gsum,
                                                   int* __restrict__ gcnt) {
    int g = blockIdx.x;
    int split = blockIdx.y;
    int tid = threadIdx.x;
    int start = lower_bound_dev(batch, N_NODES, g);
    int end = lower_bound_dev(batch, N_NODES, g + 1);
    int nodes = end - start;
    int n0 = start + (int)((long long)nodes * split / POOL_SPLITS);
    int n1 = start + (int)((long long)nodes * (split + 1) / POOL_SPLITS);
    float acc = 0.f;
    for (int n = n0; n < n1; ++n) acc += x3[(size_t)n * 256 + tid];
    atomicAdd(&gsum[g * 256 + tid], acc);
    if (split == 0 && tid == 0) gcnt[g] = nodes;
}

// ---------------------------------------------------------------- head MLP
__global__ __launch_bounds__(256) void fc1_kernel(const float* __restrict__ gsum,
                                                  const int* __restrict__ gcnt,
                                                  const float* __restrict__ w,
                                                  const float* __restrict__ b,
                                                  float* __restrict__ h1) {
    __shared__ float gc[256];
    int g = blockIdx.x;
    int tid = threadIdx.x;
    float denom = fmaxf((float)gcnt[g], 1.0f);
    gc[tid] = gsum[g * 256 + tid] / denom;
    __syncthreads();
#pragma unroll
    for (int jj = 0; jj < 2; ++jj) {
        int j = tid + jj * 256;
        float sum = b[j];
        for (int k = 0; k < 256; ++k) sum += gc[k] * w[k * HID + j];
        h1[g * HID + j] = (sum > 0.f) ? sum : 0.f;
    }
}

__global__ __launch_bounds__(256) void fc2_kernel(const float* __restrict__ h1,
                                                  const float* __restrict__ w,
                                                  const float* __restrict__ b,
                                                  float* __restrict__ out) {
    __shared__ float red[256];
    int g = blockIdx.x;
    int tid = threadIdx.x;
    float acc = h1[g * HID + tid] * w[tid] + h1[g * HID + tid + 256] * w[tid + 256];
    red[tid] = acc;
    __syncthreads();
    for (int off = 128; off > 0; off >>= 1) {
        if (tid < off) red[tid] += red[tid + off];
        __syncthreads();
    }
    if (tid == 0) out[g] = red[0] + b[0];
}

// ---------------------------------------------------------------- launch
extern "C" void kernel_launch(void* const* d_in, const int* in_sizes, int n_in,
                              void* d_out, int out_size, void* d_ws, size_t ws_size,
                              hipStream_t stream) {
    const float* feature  = (const float*)d_in[0];
    const int*   edge_idx = (const int*)d_in[1];
    const int*   batch    = (const int*)d_in[2];
    const float* W1    = (const float*)d_in[3];
    const float* att1  = (const float*)d_in[4];
    const float* b1    = (const float*)d_in[5];
    const float* W2    = (const float*)d_in[6];
    const float* att2  = (const float*)d_in[7];
    const float* b2    = (const float*)d_in[8];
    const float* W3    = (const float*)d_in[9];
    const float* att3  = (const float*)d_in[10];
    const float* b3    = (const float*)d_in[11];
    const float* fc1_w = (const float*)d_in[12];
    const float* fc1_b = (const float*)d_in[13];
    const float* fc2_w = (const float*)d_in[14];
    const float* fc2_b = (const float*)d_in[15];
    float* out = (float*)d_out;

    char* w = (char*)d_ws;
    auto alloc = [&](size_t bytes) {
        char* p = w;
        w += (bytes + 255) & ~(size_t)255;
        return p;
    };
    float* X1   = (float*)alloc((size_t)N_NODES * 64 * 4);
    float* X2   = (float*)alloc((size_t)N_NODES * 128 * 4);
    float* X3   = (float*)alloc((size_t)N_NODES * 256 * 4);
    float* AGG  = (float*)alloc((size_t)N_NODES * 128 * 4);
    float* ls   = (float*)alloc((size_t)N_NODES * 4);
    float* ld   = (float*)alloc((size_t)N_NODES * 4);
    float* coef = (float*)alloc((size_t)E_TOT * 4);
    float* wsd  = (float*)alloc(2 * 128 * 4);
    float* gsum = (float*)alloc(64 * 256 * 4);
    float* h1   = (float*)alloc(64 * HID * 4);
    int* cnt      = (int*)alloc((size_t)N_NODES * 4);
    int* offbuf   = (int*)alloc((size_t)N_NODES * 4);
    int* row_ptr  = (int*)alloc((size_t)(N_NODES + 1) * 4);
    int* col_idx  = (int*)alloc((size_t)E_TOT * 4);
    int* blocksum = (int*)alloc(256 * 4);
    int* blockoff = (int*)alloc(256 * 4);
    int* gcnt     = (int*)alloc(64 * 4);

    hipMemsetAsync(cnt, 0, (size_t)N_NODES * 4, stream);
    hipMemsetAsync(offbuf, 0, (size_t)N_NODES * 4, stream);
    hipMemsetAsync(gsum, 0, 64 * 256 * 4, stream);

    const int EB = (E_TOT + 255) / 256;
    const int NB = (N_NODES + 255) / 256;
    const int WB = (N_NODES * 64 + 255) / 256;   // wave-per-node grids (12500)
    const int MB = (N_NODES + 63) / 64;

    count_kernel<<<EB, 256, 0, stream>>>(edge_idx + N_EDGES, cnt);
    scan_local<<<NB, 256, 0, stream>>>(cnt, row_ptr, blocksum, N_NODES);
    scan_block<<<1, 256, 0, stream>>>(blocksum, blockoff, NB, row_ptr + N_NODES);
    scan_add<<<NB, 256, 0, stream>>>(row_ptr, blockoff, N_NODES);
    fill_kernel<<<EB, 256, 0, stream>>>(edge_idx, row_ptr, offbuf, col_idx);

    // ---- layer 1: Din=64 -> Dout=64
    fold_att_kernel<<<1, 256, 0, stream>>>(W1, att1, wsd, 64, 64);
    lsld_kernel<64><<<WB, 256, 0, stream>>>(feature, wsd, ls, ld);
    coef_kernel<<<WB, 256, 0, stream>>>(ls, ld, row_ptr, col_idx, coef);
    gather_kernel<64><<<WB, 256, 0, stream>>>(feature, coef, row_ptr, col_idx, AGG);
    sgemm_kernel<<<dim3(MB, 1), 256, 0, stream>>>(AGG, W1, X1, b1, N_NODES, 64, 64);

    // ---- layer 2: Din=64 -> Dout=128
    fold_att_kernel<<<1, 256, 0, stream>>>(W2, att2, wsd, 64, 128);
    lsld_kernel<64><<<WB, 256, 0, stream>>>(X1, wsd, ls, ld);
    coef_kernel<<<WB, 256, 0, stream>>>(ls, ld, row_ptr, col_idx, coef);
    gather_kernel<64><<<WB, 256, 0, stream>>>(X1, coef, row_ptr, col_idx, AGG);
    sgemm_kernel<<<dim3(MB, 2), 256, 0, stream>>>(AGG, W2, X2, b2, N_NODES, 128, 64);

    // ---- layer 3: Din=128 -> Dout=256
    fold_att_kernel<<<1, 256, 0, stream>>>(W3, att3, wsd, 128, 256);
    lsld_kernel<128><<<WB, 256, 0, stream>>>(X2, wsd, ls, ld);
    coef_kernel<<<WB, 256, 0, stream>>>(ls, ld, row_ptr, col_idx, coef);
    gather_kernel<128><<<WB, 256, 0, stream>>>(X2, coef, row_ptr, col_idx, AGG);
    sgemm_kernel<<<dim3(MB, 4), 256, 0, stream>>>(AGG, W3, X3, b3, N_NODES, 256, 128);

    // ---- pool + head
    pool_kernel<<<dim3(N_GRAPHS, POOL_SPLITS), 256, 0, stream>>>(X3, batch, gsum, gcnt);
    fc1_kernel<<<N_GRAPHS, 256, 0, stream>>>(gsum, gcnt, fc1_w, fc1_b, h1);
    fc2_kernel<<<N_GRAPHS, 256, 0, stream>>>(h1, fc2_w, fc2_b, out);
}

// Round 4
// 494.214 us; speedup vs baseline: 2.2421x; 1.0576x over previous
//
#include <hip/hip_runtime.h>
#include <hip/hip_bf16.h>

#define N_NODES 50000
#define N_EDGES 800000
#define E_TOT   850000   // edges + self loops
#define N_GRAPHS 64
#define HID 512

// ---------------------------------------------------------------- CSR build
__global__ __launch_bounds__(256) void count_kernel(const int* __restrict__ dst_e,
                                                    int* __restrict__ cnt) {
    int e = blockIdx.x * 256 + threadIdx.x;
    if (e >= E_TOT) return;
    int d = (e < N_EDGES) ? dst_e[e] : (e - N_EDGES);
    atomicAdd(&cnt[d], 1);
}

__global__ __launch_bounds__(256) void scan_local(const int* __restrict__ cnt,
                                                  int* __restrict__ out,
                                                  int* __restrict__ blocksum, int n) {
    __shared__ int buf[256];
    int tid = threadIdx.x;
    int i = blockIdx.x * 256 + tid;
    int v = (i < n) ? cnt[i] : 0;
    buf[tid] = v;
    __syncthreads();
    for (int off = 1; off < 256; off <<= 1) {
        int t = (tid >= off) ? buf[tid - off] : 0;
        __syncthreads();
        buf[tid] += t;
        __syncthreads();
    }
    if (i < n) out[i] = buf[tid] - v;            // exclusive
    if (tid == 255) blocksum[blockIdx.x] = buf[255];
}

__global__ __launch_bounds__(256) void scan_block(const int* __restrict__ blocksum,
                                                  int* __restrict__ blockoff, int nb,
                                                  int* __restrict__ total_ptr) {
    __shared__ int buf[256];
    int tid = threadIdx.x;
    int v = (tid < nb) ? blocksum[tid] : 0;
    buf[tid] = v;
    __syncthreads();
    for (int off = 1; off < 256; off <<= 1) {
        int t = (tid >= off) ? buf[tid - off] : 0;
        __syncthreads();
        buf[tid] += t;
        __syncthreads();
    }
    blockoff[tid] = buf[tid] - v;                // exclusive
    if (tid == 255) *total_ptr = buf[255];
}

__global__ __launch_bounds__(256) void scan_add(int* __restrict__ row_ptr,
                                                const int* __restrict__ blockoff, int n) {
    int i = blockIdx.x * 256 + threadIdx.x;
    if (i < n) row_ptr[i] += blockoff[blockIdx.x];
}

__global__ __launch_bounds__(256) void fill_kernel(const int* __restrict__ edge_index,
                                                   const int* __restrict__ row_ptr,
                                                   int* __restrict__ off,
                                                   int* __restrict__ col_idx) {
    int e = blockIdx.x * 256 + threadIdx.x;
    if (e >= E_TOT) return;
    int s, d;
    if (e < N_EDGES) { s = edge_index[e]; d = edge_index[N_EDGES + e]; }
    else             { s = e - N_EDGES;   d = s; }
    int pos = row_ptr[d] + atomicAdd(&off[d], 1);
    col_idx[pos] = s;
}

// ---------------------------------------------------------------- fold attention into input space
// wsd[0:Din] = W @ att[0,:],  wsd[Din:2Din] = W @ att[1,:]
__global__ __launch_bounds__(256) void fold_att_kernel(const float* __restrict__ W,
                                                       const float* __restrict__ att,
                                                       float* __restrict__ wsd,
                                                       int Din, int Dout) {
    int tid = threadIdx.x;
    for (int k = tid; k < 2 * Din; k += 256) {
        int half = (k >= Din) ? 1 : 0;
        int row = (k >= Din) ? (k - Din) : k;
        float s = 0.f;
        for (int j = 0; j < Dout; ++j) s += W[(size_t)row * Dout + j] * att[half * Dout + j];
        wsd[k] = s;
    }
}

// ---------------------------------------------------------------- SGEMM (f32) + bias + relu
// Optional epilogue: atomicAdd partial dots of the post-relu output tile with
// wsd_next (attention fold of the NEXT layer) into lsld_next[0:M] / [M:2M].
__global__ __launch_bounds__(256) void sgemm_kernel(const float* __restrict__ A,
                                                    const float* __restrict__ B,
                                                    float* __restrict__ C,
                                                    const float* __restrict__ bias,
                                                    const float* __restrict__ wsd_next,
                                                    float* __restrict__ lsld_next,
                                                    int M, int N, int K) {
    __shared__ float As[16][64];
    __shared__ float Bs[16][64];
    const int bm = blockIdx.x * 64;
    const int bn = blockIdx.y * 64;
    const int tid = threadIdx.x;
    const int tx = tid & 15;
    const int ty = tid >> 4;
    const int la_m = tid >> 2;
    const int la_k = (tid & 3) << 2;
    const int lb_k = tid >> 4;
    const int lb_n = (tid & 15) << 2;
    float acc[4][4] = {};
    for (int k0 = 0; k0 < K; k0 += 16) {
        float4 av = make_float4(0.f, 0.f, 0.f, 0.f);
        if (bm + la_m < M)
            av = *(const float4*)(A + (size_t)(bm + la_m) * K + k0 + la_k);
        As[la_k + 0][la_m] = av.x;
        As[la_k + 1][la_m] = av.y;
        As[la_k + 2][la_m] = av.z;
        As[la_k + 3][la_m] = av.w;
        float4 bv = *(const float4*)(B + (size_t)(k0 + lb_k) * N + bn + lb_n);
        *(float4*)&Bs[lb_k][lb_n] = bv;
        __syncthreads();
#pragma unroll
        for (int kk = 0; kk < 16; ++kk) {
            float a[4], b[4];
#pragma unroll
            for (int i = 0; i < 4; ++i) a[i] = As[kk][ty * 4 + i];
#pragma unroll
            for (int j = 0; j < 4; ++j) b[j] = Bs[kk][tx * 4 + j];
#pragma unroll
            for (int i = 0; i < 4; ++i)
#pragma unroll
                for (int j = 0; j < 4; ++j) acc[i][j] += a[i] * b[j];
        }
        __syncthreads();
    }
    float4 bv = ((const float4*)bias)[(bn >> 2) + tx];
    float4 ws = make_float4(0.f, 0.f, 0.f, 0.f), wd = ws;
    if (wsd_next) {
        ws = *(const float4*)(wsd_next + bn + tx * 4);
        wd = *(const float4*)(wsd_next + N + bn + tx * 4);
    }
#pragma unroll
    for (int i = 0; i < 4; ++i) {
        int r = bm + ty * 4 + i;
        float4 v;
        v.x = fmaxf(acc[i][0] + bv.x, 0.f);
        v.y = fmaxf(acc[i][1] + bv.y, 0.f);
        v.z = fmaxf(acc[i][2] + bv.z, 0.f);
        v.w = fmaxf(acc[i][3] + bv.w, 0.f);
        if (r < M)
            *(float4*)(C + (size_t)r * N + bn + tx * 4) = v;
        if (wsd_next) {
            float ps = v.x * ws.x + v.y * ws.y + v.z * ws.z + v.w * ws.w;
            float pd = v.x * wd.x + v.y * wd.y + v.z * wd.z + v.w * wd.w;
#pragma unroll
            for (int m = 1; m < 16; m <<= 1) {
                ps += __shfl_xor(ps, m);
                pd += __shfl_xor(pd, m);
            }
            if (tx == 0 && r < M) {
                atomicAdd(&lsld_next[r], ps);
                atomicAdd(&lsld_next[M + r], pd);
            }
        }
    }
}

// ---------------------------------------------------------------- ls/ld projections from input x (wave per node)
template <int D>
__global__ __launch_bounds__(256) void lsld_kernel(const float* __restrict__ X,
                                                   const float* __restrict__ wsd,
                                                   float* __restrict__ lsld) {
    int wid = (blockIdx.x * 256 + threadIdx.x) >> 6;
    int lane = threadIdx.x & 63;
    if (wid >= N_NODES) return;
    float a0 = 0.f, a1 = 0.f;
#pragma unroll
    for (int f = lane; f < D; f += 64) {
        float h = X[(size_t)wid * D + f];
        a0 += h * wsd[f];
        a1 += h * wsd[D + f];
    }
#pragma unroll
    for (int off = 32; off > 0; off >>= 1) {
        a0 += __shfl_xor(a0, off);
        a1 += __shfl_xor(a1, off);
    }
    if (lane == 0) { lsld[wid] = a0; lsld[N_NODES + wid] = a1; }
}

// ---------------------------------------------------------------- fused softmax + weighted gather
// one wave per dst node; lsld[0:N]=ls, lsld[N:2N]=ld
template <int D>
__global__ __launch_bounds__(256) void gather_fused_kernel(const float* __restrict__ X,
                                                           const float* __restrict__ lsld,
                                                           const int* __restrict__ row_ptr,
                                                           const int* __restrict__ col_idx,
                                                           float* __restrict__ out) {
    constexpr int L = D / 4;     // lanes per edge
    constexpr int P = 64 / L;    // edges handled concurrently by one wave
    int wid = (blockIdx.x * 256 + threadIdx.x) >> 6;
    int lane = threadIdx.x & 63;
    if (wid >= N_NODES) return;
    const int start = row_ptr[wid];
    const int end = row_ptr[wid + 1];
    const int deg = end - start;
    const float ldi = lsld[N_NODES + wid];
    const float* __restrict__ ls = lsld;
    const int eslot = lane / L;
    const int fidx = lane % L;
    const float4* __restrict__ X4 = (const float4*)X;
    float4 acc = make_float4(0.f, 0.f, 0.f, 0.f);

    if (deg <= 64) {
        // per-edge coef in registers (edge ordinal == lane)
        int srcl = 0;
        float l = -3.0e38f;
        if (lane < deg) {
            srcl = col_idx[start + lane];
            float t = ls[srcl] + ldi;
            l = (t > 0.f) ? t : 0.2f * t;
        }
        float m = l;
#pragma unroll
        for (int off = 32; off > 0; off >>= 1) m = fmaxf(m, __shfl_xor(m, off));
        float e = (lane < deg) ? __expf(l - m) : 0.f;
        float s = e;
#pragma unroll
        for (int off = 32; off > 0; off >>= 1) s += __shfl_xor(s, off);
        const float cl = e / s;

        for (int e0 = 0; e0 < deg; e0 += 8 * P) {
#pragma unroll
            for (int j = 0; j < 8; ++j) {
                int idx = e0 + j * P + eslot;
                bool valid = idx < deg;
                float c = __shfl(cl, idx);
                int src = __shfl(srcl, idx);
                c = valid ? c : 0.f;
                src = valid ? src : 0;
                float4 v = X4[(size_t)src * L + fidx];
                acc.x += c * v.x;
                acc.y += c * v.y;
                acc.z += c * v.z;
                acc.w += c * v.w;
            }
        }
    } else {
        // rare high-degree path: strided passes, recompute coef during gather
        float m = -3.0e38f;
        for (int e = start + lane; e < end; e += 64) {
            float t = ls[col_idx[e]] + ldi;
            t = (t > 0.f) ? t : 0.2f * t;
            m = fmaxf(m, t);
        }
#pragma unroll
        for (int off = 32; off > 0; off >>= 1) m = fmaxf(m, __shfl_xor(m, off));
        float ssum = 0.f;
        for (int e = start + lane; e < end; e += 64) {
            float t = ls[col_idx[e]] + ldi;
            t = (t > 0.f) ? t : 0.2f * t;
            ssum += __expf(t - m);
        }
#pragma unroll
        for (int off = 32; off > 0; off >>= 1) ssum += __shfl_xor(ssum, off);
        const float inv = 1.0f / ssum;
        for (int e0 = start; e0 < end; e0 += P) {
            int e = e0 + eslot;
            if (e < end) {
                int src = col_idx[e];
                float t = ls[src] + ldi;
                t = (t > 0.f) ? t : 0.2f * t;
                float c = __expf(t - m) * inv;
                float4 v = X4[(size_t)src * L + fidx];
                acc.x += c * v.x;
                acc.y += c * v.y;
                acc.z += c * v.z;
                acc.w += c * v.w;
            }
        }
    }
#pragma unroll
    for (int mm = L; mm < 64; mm <<= 1) {
        acc.x += __shfl_xor(acc.x, mm);
        acc.y += __shfl_xor(acc.y, mm);
        acc.z += __shfl_xor(acc.z, mm);
        acc.w += __shfl_xor(acc.w, mm);
    }
    if (eslot == 0)
        ((float4*)out)[(size_t)wid * L + fidx] = acc;
}

// ---------------------------------------------------------------- mean pool (sorted batch)
__device__ inline int lower_bound_dev(const int* __restrict__ a, int n, int v) {
    int lo = 0, hi = n;
    while (lo < hi) { int mid = (lo + hi) >> 1; if (a[mid] < v) lo = mid + 1; else hi = mid; }
    return lo;
}

#define POOL_SPLITS 32
__global__ __launch_bounds__(256) void pool_kernel(const float* __restrict__ x3,
                                                   const int* __restrict__ batch,
                                                   float* __restrict__ gsum,
                                                   int* __restrict__ gcnt) {
    int g = blockIdx.x;
    int split = blockIdx.y;
    int tid = threadIdx.x;
    int start = lower_bound_dev(batch, N_NODES, g);
    int end = lower_bound_dev(batch, N_NODES, g + 1);
    int nodes = end - start;
    int n0 = start + (int)((long long)nodes * split / POOL_SPLITS);
    int n1 = start + (int)((long long)nodes * (split + 1) / POOL_SPLITS);
    float acc = 0.f;
    for (int n = n0; n < n1; ++n) acc += x3[(size_t)n * 256 + tid];
    atomicAdd(&gsum[g * 256 + tid], acc);
    if (split == 0 && tid == 0) gcnt[g] = nodes;
}

// ---------------------------------------------------------------- head MLP
__global__ __launch_bounds__(256) void fc1_kernel(const float* __restrict__ gsum,
                                                  const int* __restrict__ gcnt,
                                                  const float* __restrict__ w,
                                                  const float* __restrict__ b,
                                                  float* __restrict__ h1) {
    __shared__ float gc[256];
    int g = blockIdx.x;
    int tid = threadIdx.x;
    float denom = fmaxf((float)gcnt[g], 1.0f);
    gc[tid] = gsum[g * 256 + tid] / denom;
    __syncthreads();
#pragma unroll
    for (int jj = 0; jj < 2; ++jj) {
        int j = tid + jj * 256;
        float sum = b[j];
        for (int k = 0; k < 256; ++k) sum += gc[k] * w[k * HID + j];
        h1[g * HID + j] = (sum > 0.f) ? sum : 0.f;
    }
}

__global__ __launch_bounds__(256) void fc2_kernel(const float* __restrict__ h1,
                                                  const float* __restrict__ w,
                                                  const float* __restrict__ b,
                                                  float* __restrict__ out) {
    __shared__ float red[256];
    int g = blockIdx.x;
    int tid = threadIdx.x;
    float acc = h1[g * HID + tid] * w[tid] + h1[g * HID + tid + 256] * w[tid + 256];
    red[tid] = acc;
    __syncthreads();
    for (int off = 128; off > 0; off >>= 1) {
        if (tid < off) red[tid] += red[tid + off];
        __syncthreads();
    }
    if (tid == 0) out[g] = red[0] + b[0];
}

// ---------------------------------------------------------------- launch
extern "C" void kernel_launch(void* const* d_in, const int* in_sizes, int n_in,
                              void* d_out, int out_size, void* d_ws, size_t ws_size,
                              hipStream_t stream) {
    const float* feature  = (const float*)d_in[0];
    const int*   edge_idx = (const int*)d_in[1];
    const int*   batch    = (const int*)d_in[2];
    const float* W1    = (const float*)d_in[3];
    const float* att1  = (const float*)d_in[4];
    const float* b1    = (const float*)d_in[5];
    const float* W2    = (const float*)d_in[6];
    const float* att2  = (const float*)d_in[7];
    const float* b2    = (const float*)d_in[8];
    const float* W3    = (const float*)d_in[9];
    const float* att3  = (const float*)d_in[10];
    const float* b3    = (const float*)d_in[11];
    const float* fc1_w = (const float*)d_in[12];
    const float* fc1_b = (const float*)d_in[13];
    const float* fc2_w = (const float*)d_in[14];
    const float* fc2_b = (const float*)d_in[15];
    float* out = (float*)d_out;

    char* w = (char*)d_ws;
    auto alloc = [&](size_t bytes) {
        char* p = w;
        w += (bytes + 255) & ~(size_t)255;
        return p;
    };
    float* X1    = (float*)alloc((size_t)N_NODES * 64 * 4);
    float* X2    = (float*)alloc((size_t)N_NODES * 128 * 4);
    float* X3    = (float*)alloc((size_t)N_NODES * 256 * 4);
    float* AGG   = (float*)alloc((size_t)N_NODES * 128 * 4);
    float* lsld1 = (float*)alloc((size_t)N_NODES * 2 * 4);
    float* lsld2 = (float*)alloc((size_t)N_NODES * 2 * 4);   // zeroed (contiguous with lsld3)
    float* lsld3 = (float*)alloc((size_t)N_NODES * 2 * 4);   // zeroed
    float* wsd1  = (float*)alloc(2 * 64 * 4);
    float* wsd2  = (float*)alloc(2 * 64 * 4);
    float* wsd3  = (float*)alloc(2 * 128 * 4);
    float* gsum  = (float*)alloc(64 * 256 * 4);
    float* h1    = (float*)alloc(64 * HID * 4);
    int* cnt      = (int*)alloc((size_t)N_NODES * 4);
    int* offbuf   = (int*)alloc((size_t)N_NODES * 4);
    int* row_ptr  = (int*)alloc((size_t)(N_NODES + 1) * 4);
    int* col_idx  = (int*)alloc((size_t)E_TOT * 4);
    int* blocksum = (int*)alloc(256 * 4);
    int* blockoff = (int*)alloc(256 * 4);
    int* gcnt     = (int*)alloc(64 * 4);

    hipMemsetAsync(cnt, 0, (size_t)N_NODES * 4, stream);
    hipMemsetAsync(offbuf, 0, (size_t)N_NODES * 4, stream);
    hipMemsetAsync(gsum, 0, 64 * 256 * 4, stream);
    hipMemsetAsync(lsld2, 0, (size_t)N_NODES * 4 * 4, stream);  // lsld2 + lsld3

    const int EB = (E_TOT + 255) / 256;
    const int NB = (N_NODES + 255) / 256;
    const int WB = (N_NODES * 64 + 255) / 256;   // wave-per-node grids (12500)
    const int MB = (N_NODES + 63) / 64;

    // attention folds (independent of everything else)
    fold_att_kernel<<<1, 256, 0, stream>>>(W1, att1, wsd1, 64, 64);
    fold_att_kernel<<<1, 256, 0, stream>>>(W2, att2, wsd2, 64, 128);
    fold_att_kernel<<<1, 256, 0, stream>>>(W3, att3, wsd3, 128, 256);

    count_kernel<<<EB, 256, 0, stream>>>(edge_idx + N_EDGES, cnt);
    scan_local<<<NB, 256, 0, stream>>>(cnt, row_ptr, blocksum, N_NODES);
    scan_block<<<1, 256, 0, stream>>>(blocksum, blockoff, NB, row_ptr + N_NODES);
    scan_add<<<NB, 256, 0, stream>>>(row_ptr, blockoff, N_NODES);
    fill_kernel<<<EB, 256, 0, stream>>>(edge_idx, row_ptr, offbuf, col_idx);

    // ---- layer 1: Din=64 -> Dout=64
    lsld_kernel<64><<<WB, 256, 0, stream>>>(feature, wsd1, lsld1);
    gather_fused_kernel<64><<<WB, 256, 0, stream>>>(feature, lsld1, row_ptr, col_idx, AGG);
    sgemm_kernel<<<dim3(MB, 1), 256, 0, stream>>>(AGG, W1, X1, b1, wsd2, lsld2, N_NODES, 64, 64);

    // ---- layer 2: Din=64 -> Dout=128
    gather_fused_kernel<64><<<WB, 256, 0, stream>>>(X1, lsld2, row_ptr, col_idx, AGG);
    sgemm_kernel<<<dim3(MB, 2), 256, 0, stream>>>(AGG, W2, X2, b2, wsd3, lsld3, N_NODES, 128, 64);

    // ---- layer 3: Din=128 -> Dout=256
    gather_fused_kernel<128><<<WB, 256, 0, stream>>>(X2, lsld3, row_ptr, col_idx, AGG);
    sgemm_kernel<<<dim3(MB, 4), 256, 0, stream>>>(AGG, W3, X3, b3, nullptr, nullptr, N_NODES, 256, 128);

    // ---- pool + head
    pool_kernel<<<dim3(N_GRAPHS, POOL_SPLITS), 256, 0, stream>>>(X3, batch, gsum, gcnt);
    fc1_kernel<<<N_GRAPHS, 256, 0, stream>>>(gsum, gcnt, fc1_w, fc1_b, h1);
    fc2_kernel<<<N_GRAPHS, 256, 0, stream>>>(h1, fc2_w, fc2_b, out);
}

// Round 5
// 486.381 us; speedup vs baseline: 2.2782x; 1.0161x over previous
//
#include <hip/hip_runtime.h>
#include <hip/hip_bf16.h>

#define N_NODES 50000
#define N_EDGES 800000
#define E_TOT   850000   // edges + self loops
#define N_GRAPHS 64
#define HID 512

// ---------------------------------------------------------------- CSR build
__global__ __launch_bounds__(256) void count_kernel(const int* __restrict__ dst_e,
                                                    int* __restrict__ cnt) {
    int e = blockIdx.x * 256 + threadIdx.x;
    if (e >= E_TOT) return;
    int d = (e < N_EDGES) ? dst_e[e] : (e - N_EDGES);
    atomicAdd(&cnt[d], 1);
}

__global__ __launch_bounds__(256) void scan_local(const int* __restrict__ cnt,
                                                  int* __restrict__ out,
                                                  int* __restrict__ blocksum, int n) {
    __shared__ int buf[256];
    int tid = threadIdx.x;
    int i = blockIdx.x * 256 + tid;
    int v = (i < n) ? cnt[i] : 0;
    buf[tid] = v;
    __syncthreads();
    for (int off = 1; off < 256; off <<= 1) {
        int t = (tid >= off) ? buf[tid - off] : 0;
        __syncthreads();
        buf[tid] += t;
        __syncthreads();
    }
    if (i < n) out[i] = buf[tid] - v;            // exclusive
    if (tid == 255) blocksum[blockIdx.x] = buf[255];
}

__global__ __launch_bounds__(256) void scan_block(const int* __restrict__ blocksum,
                                                  int* __restrict__ blockoff, int nb,
                                                  int* __restrict__ total_ptr) {
    __shared__ int buf[256];
    int tid = threadIdx.x;
    int v = (tid < nb) ? blocksum[tid] : 0;
    buf[tid] = v;
    __syncthreads();
    for (int off = 1; off < 256; off <<= 1) {
        int t = (tid >= off) ? buf[tid - off] : 0;
        __syncthreads();
        buf[tid] += t;
        __syncthreads();
    }
    blockoff[tid] = buf[tid] - v;                // exclusive
    if (tid == 255) *total_ptr = buf[255];
}

__global__ __launch_bounds__(256) void scan_add(int* __restrict__ row_ptr,
                                                const int* __restrict__ blockoff, int n) {
    int i = blockIdx.x * 256 + threadIdx.x;
    if (i < n) row_ptr[i] += blockoff[blockIdx.x];
}

__global__ __launch_bounds__(256) void fill_kernel(const int* __restrict__ edge_index,
                                                   const int* __restrict__ row_ptr,
                                                   int* __restrict__ off,
                                                   int* __restrict__ col_idx) {
    int e = blockIdx.x * 256 + threadIdx.x;
    if (e >= E_TOT) return;
    int s, d;
    if (e < N_EDGES) { s = edge_index[e]; d = edge_index[N_EDGES + e]; }
    else             { s = e - N_EDGES;   d = s; }
    int pos = row_ptr[d] + atomicAdd(&off[d], 1);
    col_idx[pos] = s;
}

// ---------------------------------------------------------------- fold attention into input space
// wsd[0:Din] = W @ att[0,:],  wsd[Din:2Din] = W @ att[1,:]
__global__ __launch_bounds__(256) void fold_att_kernel(const float* __restrict__ W,
                                                       const float* __restrict__ att,
                                                       float* __restrict__ wsd,
                                                       int Din, int Dout) {
    int tid = threadIdx.x;
    for (int k = tid; k < 2 * Din; k += 256) {
        int half = (k >= Din) ? 1 : 0;
        int row = (k >= Din) ? (k - Din) : k;
        float s = 0.f;
        for (int j = 0; j < Dout; ++j) s += W[(size_t)row * Dout + j] * att[half * Dout + j];
        wsd[k] = s;
    }
}

// ---------------------------------------------------------------- SGEMM (f32) + bias + relu
// Optional epilogue: atomicAdd partial dots of the post-relu output tile with
// wsd_next (attention fold of the NEXT layer) into lsld_next[0:M] / [M:2M].
__global__ __launch_bounds__(256) void sgemm_kernel(const float* __restrict__ A,
                                                    const float* __restrict__ B,
                                                    float* __restrict__ C,
                                                    const float* __restrict__ bias,
                                                    const float* __restrict__ wsd_next,
                                                    float* __restrict__ lsld_next,
                                                    int M, int N, int K) {
    __shared__ float As[16][64];
    __shared__ float Bs[16][64];
    const int bm = blockIdx.x * 64;
    const int bn = blockIdx.y * 64;
    const int tid = threadIdx.x;
    const int tx = tid & 15;
    const int ty = tid >> 4;
    const int la_m = tid >> 2;
    const int la_k = (tid & 3) << 2;
    const int lb_k = tid >> 4;
    const int lb_n = (tid & 15) << 2;
    float acc[4][4] = {};
    for (int k0 = 0; k0 < K; k0 += 16) {
        float4 av = make_float4(0.f, 0.f, 0.f, 0.f);
        if (bm + la_m < M)
            av = *(const float4*)(A + (size_t)(bm + la_m) * K + k0 + la_k);
        As[la_k + 0][la_m] = av.x;
        As[la_k + 1][la_m] = av.y;
        As[la_k + 2][la_m] = av.z;
        As[la_k + 3][la_m] = av.w;
        float4 bv = *(const float4*)(B + (size_t)(k0 + lb_k) * N + bn + lb_n);
        *(float4*)&Bs[lb_k][lb_n] = bv;
        __syncthreads();
#pragma unroll
        for (int kk = 0; kk < 16; ++kk) {
            float a[4], b[4];
#pragma unroll
            for (int i = 0; i < 4; ++i) a[i] = As[kk][ty * 4 + i];
#pragma unroll
            for (int j = 0; j < 4; ++j) b[j] = Bs[kk][tx * 4 + j];
#pragma unroll
            for (int i = 0; i < 4; ++i)
#pragma unroll
                for (int j = 0; j < 4; ++j) acc[i][j] += a[i] * b[j];
        }
        __syncthreads();
    }
    float4 bv = ((const float4*)bias)[(bn >> 2) + tx];
    float4 ws = make_float4(0.f, 0.f, 0.f, 0.f), wd = ws;
    if (wsd_next) {
        ws = *(const float4*)(wsd_next + bn + tx * 4);
        wd = *(const float4*)(wsd_next + N + bn + tx * 4);
    }
#pragma unroll
    for (int i = 0; i < 4; ++i) {
        int r = bm + ty * 4 + i;
        float4 v;
        v.x = fmaxf(acc[i][0] + bv.x, 0.f);
        v.y = fmaxf(acc[i][1] + bv.y, 0.f);
        v.z = fmaxf(acc[i][2] + bv.z, 0.f);
        v.w = fmaxf(acc[i][3] + bv.w, 0.f);
        if (r < M)
            *(float4*)(C + (size_t)r * N + bn + tx * 4) = v;
        if (wsd_next) {
            float ps = v.x * ws.x + v.y * ws.y + v.z * ws.z + v.w * ws.w;
            float pd = v.x * wd.x + v.y * wd.y + v.z * wd.z + v.w * wd.w;
#pragma unroll
            for (int m = 1; m < 16; m <<= 1) {
                ps += __shfl_xor(ps, m);
                pd += __shfl_xor(pd, m);
            }
            if (tx == 0 && r < M) {
                atomicAdd(&lsld_next[r], ps);
                atomicAdd(&lsld_next[M + r], pd);
            }
        }
    }
}

// ---------------------------------------------------------------- ls/ld projections from input x (wave per node)
template <int D>
__global__ __launch_bounds__(256) void lsld_kernel(const float* __restrict__ X,
                                                   const float* __restrict__ wsd,
                                                   float* __restrict__ lsld) {
    int wid = (blockIdx.x * 256 + threadIdx.x) >> 6;
    int lane = threadIdx.x & 63;
    if (wid >= N_NODES) return;
    float a0 = 0.f, a1 = 0.f;
#pragma unroll
    for (int f = lane; f < D; f += 64) {
        float h = X[(size_t)wid * D + f];
        a0 += h * wsd[f];
        a1 += h * wsd[D + f];
    }
#pragma unroll
    for (int off = 32; off > 0; off >>= 1) {
        a0 += __shfl_xor(a0, off);
        a1 += __shfl_xor(a1, off);
    }
    if (lane == 0) { lsld[wid] = a0; lsld[N_NODES + wid] = a1; }
}

// ---------------------------------------------------------------- fused softmax + weighted gather
// one wave per dst node; lsld[0:N]=ls, lsld[N:2N]=ld.
// (src, coef) staged in wave-private LDS; gather loop = R3 shape (4-wide main + guarded tail).
template <int D>
__global__ __launch_bounds__(256) void gather_fused_kernel(const float* __restrict__ X,
                                                           const float* __restrict__ lsld,
                                                           const int* __restrict__ row_ptr,
                                                           const int* __restrict__ col_idx,
                                                           float* __restrict__ out) {
    constexpr int L = D / 4;     // lanes per edge
    constexpr int P = 64 / L;    // edges handled concurrently by one wave
    __shared__ float2 ec_all[4][64];   // per-wave (coef, src) staging
    int wid = (blockIdx.x * 256 + threadIdx.x) >> 6;
    int lane = threadIdx.x & 63;
    if (wid >= N_NODES) return;
    float2* __restrict__ ec = ec_all[(threadIdx.x >> 6)];
    const int start = row_ptr[wid];
    const int end = row_ptr[wid + 1];
    const int deg = end - start;
    const float ldi = lsld[N_NODES + wid];
    const float* __restrict__ ls = lsld;
    const int eslot = lane / L;
    const int fidx = lane % L;
    const float4* __restrict__ X4 = (const float4*)X;
    float4 acc = make_float4(0.f, 0.f, 0.f, 0.f);

    if (deg <= 64) {
        // softmax in registers (edge ordinal == lane), stage (coef, src) to LDS
        int srcl = 0;
        float l = -3.0e38f;
        if (lane < deg) {
            srcl = col_idx[start + lane];
            float t = ls[srcl] + ldi;
            l = (t > 0.f) ? t : 0.2f * t;
        }
        float m = l;
#pragma unroll
        for (int off = 32; off > 0; off >>= 1) m = fmaxf(m, __shfl_xor(m, off));
        float e = (lane < deg) ? __expf(l - m) : 0.f;
        float s = e;
#pragma unroll
        for (int off = 32; off > 0; off >>= 1) s += __shfl_xor(s, off);
        ec[lane] = make_float2(e / s, __int_as_float(srcl));
        // wave-synchronous: ds_write -> ds_read ordered within the wave (compiler waits lgkmcnt)

        int e0 = 0;
        for (; e0 + 4 * P <= deg; e0 += 4 * P) {
            float2 p[4]; float4 v[4];
#pragma unroll
            for (int j = 0; j < 4; ++j) p[j] = ec[e0 + j * P + eslot];
#pragma unroll
            for (int j = 0; j < 4; ++j)
                v[j] = X4[(size_t)__float_as_int(p[j].y) * L + fidx];
#pragma unroll
            for (int j = 0; j < 4; ++j) {
                acc.x += p[j].x * v[j].x;
                acc.y += p[j].x * v[j].y;
                acc.z += p[j].x * v[j].z;
                acc.w += p[j].x * v[j].w;
            }
        }
        for (; e0 < deg; e0 += P) {
            int idx = e0 + eslot;
            if (idx < deg) {
                float2 p = ec[idx];
                float4 v = X4[(size_t)__float_as_int(p.y) * L + fidx];
                acc.x += p.x * v.x;
                acc.y += p.x * v.y;
                acc.z += p.x * v.z;
                acc.w += p.x * v.w;
            }
        }
    } else {
        // rare high-degree path: strided passes, recompute coef during gather
        float m = -3.0e38f;
        for (int e = start + lane; e < end; e += 64) {
            float t = ls[col_idx[e]] + ldi;
            t = (t > 0.f) ? t : 0.2f * t;
            m = fmaxf(m, t);
        }
#pragma unroll
        for (int off = 32; off > 0; off >>= 1) m = fmaxf(m, __shfl_xor(m, off));
        float ssum = 0.f;
        for (int e = start + lane; e < end; e += 64) {
            float t = ls[col_idx[e]] + ldi;
            t = (t > 0.f) ? t : 0.2f * t;
            ssum += __expf(t - m);
        }
#pragma unroll
        for (int off = 32; off > 0; off >>= 1) ssum += __shfl_xor(ssum, off);
        const float inv = 1.0f / ssum;
        for (int e0 = start; e0 < end; e0 += P) {
            int e = e0 + eslot;
            if (e < end) {
                int src = col_idx[e];
                float t = ls[src] + ldi;
                t = (t > 0.f) ? t : 0.2f * t;
                float c = __expf(t - m) * inv;
                float4 v = X4[(size_t)src * L + fidx];
                acc.x += c * v.x;
                acc.y += c * v.y;
                acc.z += c * v.z;
                acc.w += c * v.w;
            }
        }
    }
#pragma unroll
    for (int mm = L; mm < 64; mm <<= 1) {
        acc.x += __shfl_xor(acc.x, mm);
        acc.y += __shfl_xor(acc.y, mm);
        acc.z += __shfl_xor(acc.z, mm);
        acc.w += __shfl_xor(acc.w, mm);
    }
    if (eslot == 0)
        ((float4*)out)[(size_t)wid * L + fidx] = acc;
}

// ---------------------------------------------------------------- mean pool (sorted batch)
__device__ inline int lower_bound_dev(const int* __restrict__ a, int n, int v) {
    int lo = 0, hi = n;
    while (lo < hi) { int mid = (lo + hi) >> 1; if (a[mid] < v) lo = mid + 1; else hi = mid; }
    return lo;
}

#define POOL_SPLITS 32
__global__ __launch_bounds__(256) void pool_kernel(const float* __restrict__ x3,
                                                   const int* __restrict__ batch,
                                                   float* __restrict__ gsum,
                                                   int* __restrict__ gcnt) {
    int g = blockIdx.x;
    int split = blockIdx.y;
    int tid = threadIdx.x;
    int start = lower_bound_dev(batch, N_NODES, g);
    int end = lower_bound_dev(batch, N_NODES, g + 1);
    int nodes = end - start;
    int n0 = start + (int)((long long)nodes * split / POOL_SPLITS);
    int n1 = start + (int)((long long)nodes * (split + 1) / POOL_SPLITS);
    float acc = 0.f;
    for (int n = n0; n < n1; ++n) acc += x3[(size_t)n * 256 + tid];
    atomicAdd(&gsum[g * 256 + tid], acc);
    if (split == 0 && tid == 0) gcnt[g] = nodes;
}

// ---------------------------------------------------------------- head MLP
__global__ __launch_bounds__(256) void fc1_kernel(const float* __restrict__ gsum,
                                                  const int* __restrict__ gcnt,
                                                  const float* __restrict__ w,
                                                  const float* __restrict__ b,
                                                  float* __restrict__ h1) {
    __shared__ float gc[256];
    int g = blockIdx.x;
    int tid = threadIdx.x;
    float denom = fmaxf((float)gcnt[g], 1.0f);
    gc[tid] = gsum[g * 256 + tid] / denom;
    __syncthreads();
#pragma unroll
    for (int jj = 0; jj < 2; ++jj) {
        int j = tid + jj * 256;
        float sum = b[j];
        for (int k = 0; k < 256; ++k) sum += gc[k] * w[k * HID + j];
        h1[g * HID + j] = (sum > 0.f) ? sum : 0.f;
    }
}

__global__ __launch_bounds__(256) void fc2_kernel(const float* __restrict__ h1,
                                                  const float* __restrict__ w,
                                                  const float* __restrict__ b,
                                                  float* __restrict__ out) {
    __shared__ float red[256];
    int g = blockIdx.x;
    int tid = threadIdx.x;
    float acc = h1[g * HID + tid] * w[tid] + h1[g * HID + tid + 256] * w[tid + 256];
    red[tid] = acc;
    __syncthreads();
    for (int off = 128; off > 0; off >>= 1) {
        if (tid < off) red[tid] += red[tid + off];
        __syncthreads();
    }
    if (tid == 0) out[g] = red[0] + b[0];
}

// ---------------------------------------------------------------- launch
extern "C" void kernel_launch(void* const* d_in, const int* in_sizes, int n_in,
                              void* d_out, int out_size, void* d_ws, size_t ws_size,
                              hipStream_t stream) {
    const float* feature  = (const float*)d_in[0];
    const int*   edge_idx = (const int*)d_in[1];
    const int*   batch    = (const int*)d_in[2];
    const float* W1    = (const float*)d_in[3];
    const float* att1  = (const float*)d_in[4];
    const float* b1    = (const float*)d_in[5];
    const float* W2    = (const float*)d_in[6];
    const float* att2  = (const float*)d_in[7];
    const float* b2    = (const float*)d_in[8];
    const float* W3    = (const float*)d_in[9];
    const float* att3  = (const float*)d_in[10];
    const float* b3    = (const float*)d_in[11];
    const float* fc1_w = (const float*)d_in[12];
    const float* fc1_b = (const float*)d_in[13];
    const float* fc2_w = (const float*)d_in[14];
    const float* fc2_b = (const float*)d_in[15];
    float* out = (float*)d_out;

    char* w = (char*)d_ws;
    auto alloc = [&](size_t bytes) {
        char* p = w;
        w += (bytes + 255) & ~(size_t)255;
        return p;
    };
    float* X1    = (float*)alloc((size_t)N_NODES * 64 * 4);
    float* X2    = (float*)alloc((size_t)N_NODES * 128 * 4);
    float* X3    = (float*)alloc((size_t)N_NODES * 256 * 4);
    float* AGG   = (float*)alloc((size_t)N_NODES * 128 * 4);
    float* lsld1 = (float*)alloc((size_t)N_NODES * 2 * 4);
    float* lsld2 = (float*)alloc((size_t)N_NODES * 2 * 4);   // zeroed (contiguous with lsld3)
    float* lsld3 = (float*)alloc((size_t)N_NODES * 2 * 4);   // zeroed
    float* wsd1  = (float*)alloc(2 * 64 * 4);
    float* wsd2  = (float*)alloc(2 * 64 * 4);
    float* wsd3  = (float*)alloc(2 * 128 * 4);
    float* gsum  = (float*)alloc(64 * 256 * 4);
    float* h1    = (float*)alloc(64 * HID * 4);
    int* cnt      = (int*)alloc((size_t)N_NODES * 4);
    int* offbuf   = (int*)alloc((size_t)N_NODES * 4);
    int* row_ptr  = (int*)alloc((size_t)(N_NODES + 1) * 4);
    int* col_idx  = (int*)alloc((size_t)E_TOT * 4);
    int* blocksum = (int*)alloc(256 * 4);
    int* blockoff = (int*)alloc(256 * 4);
    int* gcnt     = (int*)alloc(64 * 4);

    hipMemsetAsync(cnt, 0, (size_t)N_NODES * 4, stream);
    hipMemsetAsync(offbuf, 0, (size_t)N_NODES * 4, stream);
    hipMemsetAsync(gsum, 0, 64 * 256 * 4, stream);
    hipMemsetAsync(lsld2, 0, (size_t)N_NODES * 4 * 4, stream);  // lsld2 + lsld3

    const int EB = (E_TOT + 255) / 256;
    const int NB = (N_NODES + 255) / 256;
    const int WB = (N_NODES * 64 + 255) / 256;   // wave-per-node grids (12500)
    const int MB = (N_NODES + 63) / 64;

    // attention folds (independent of everything else)
    fold_att_kernel<<<1, 256, 0, stream>>>(W1, att1, wsd1, 64, 64);
    fold_att_kernel<<<1, 256, 0, stream>>>(W2, att2, wsd2, 64, 128);
    fold_att_kernel<<<1, 256, 0, stream>>>(W3, att3, wsd3, 128, 256);

    count_kernel<<<EB, 256, 0, stream>>>(edge_idx + N_EDGES, cnt);
    scan_local<<<NB, 256, 0, stream>>>(cnt, row_ptr, blocksum, N_NODES);
    scan_block<<<1, 256, 0, stream>>>(blocksum, blockoff, NB, row_ptr + N_NODES);
    scan_add<<<NB, 256, 0, stream>>>(row_ptr, blockoff, N_NODES);
    fill_kernel<<<EB, 256, 0, stream>>>(edge_idx, row_ptr, offbuf, col_idx);

    // ---- layer 1: Din=64 -> Dout=64
    lsld_kernel<64><<<WB, 256, 0, stream>>>(feature, wsd1, lsld1);
    gather_fused_kernel<64><<<WB, 256, 0, stream>>>(feature, lsld1, row_ptr, col_idx, AGG);
    sgemm_kernel<<<dim3(MB, 1), 256, 0, stream>>>(AGG, W1, X1, b1, wsd2, lsld2, N_NODES, 64, 64);

    // ---- layer 2: Din=64 -> Dout=128
    gather_fused_kernel<64><<<WB, 256, 0, stream>>>(X1, lsld2, row_ptr, col_idx, AGG);
    sgemm_kernel<<<dim3(MB, 2), 256, 0, stream>>>(AGG, W2, X2, b2, wsd3, lsld3, N_NODES, 128, 64);

    // ---- layer 3: Din=128 -> Dout=256
    gather_fused_kernel<128><<<WB, 256, 0, stream>>>(X2, lsld3, row_ptr, col_idx, AGG);
    sgemm_kernel<<<dim3(MB, 4), 256, 0, stream>>>(AGG, W3, X3, b3, nullptr, nullptr, N_NODES, 256, 128);

    // ---- pool + head
    pool_kernel<<<dim3(N_GRAPHS, POOL_SPLITS), 256, 0, stream>>>(X3, batch, gsum, gcnt);
    fc1_kernel<<<N_GRAPHS, 256, 0, stream>>>(gsum, gcnt, fc1_w, fc1_b, h1);
    fc2_kernel<<<N_GRAPHS, 256, 0, stream>>>(h1, fc2_w, fc2_b, out);
}